// Round 5
// baseline (338.104 us; speedup 1.0000x reference)
//
#include <hip/hip_runtime.h>
#include <hip/hip_bf16.h>
#include <stdint.h>

#define T_TOK 8192
#define D_IN  1024
#define N_EXP 8
#define D_OUT 1024

#define BM 128
#define BN 128

typedef short s8v __attribute__((ext_vector_type(8)));
typedef float f4v __attribute__((ext_vector_type(4)));
typedef unsigned short ushort_t;

__device__ __forceinline__ ushort_t f2bf(float f) {
    uint32_t u = __float_as_uint(f);
    uint32_t r = (u + 0x7fffu + ((u >> 16) & 1u)) >> 16;
    return (ushort_t)r;
}

__device__ __forceinline__ float bf2f(ushort_t u) {
    return __uint_as_float(((uint32_t)u) << 16);
}

// ------- cast + transpose We -> bf16 [E][DOUT][D]; block0 zeroes counters ---
__global__ void cast_transpose_we(const float* __restrict__ We,
                                  ushort_t* __restrict__ Webt,
                                  int* __restrict__ cnt,
                                  float* __restrict__ psum) {
    if (blockIdx.x == 0 && blockIdx.y == 0 && blockIdx.z == 0 &&
        threadIdx.x < N_EXP) {
        cnt[threadIdx.x] = 0;
        psum[threadIdx.x] = 0.f;
    }
    __shared__ float tile[64][65];
    int e  = blockIdx.z;
    int k0 = blockIdx.y * 64;   // D index
    int h0 = blockIdx.x * 64;   // DOUT index
    int tid = threadIdx.x;
    const float* src = We + ((size_t)e * D_IN + k0) * D_OUT + h0;
#pragma unroll
    for (int it = 0; it < 4; ++it) {
        int lin = it * 256 + tid;
        int r = lin >> 4;
        int c4 = (lin & 15) * 4;
        float4 v = *(const float4*)(src + (size_t)r * D_OUT + c4);
        tile[r][c4]     = v.x; tile[r][c4 + 1] = v.y;
        tile[r][c4 + 2] = v.z; tile[r][c4 + 3] = v.w;
    }
    __syncthreads();
    ushort_t* dst = Webt + ((size_t)e * D_OUT + h0) * D_IN + k0;
#pragma unroll
    for (int it = 0; it < 4; ++it) {
        int lin = it * 256 + tid;
        int h = lin >> 4;
        int k4 = (lin & 15) * 4;
        ushort4 u;
        u.x = f2bf(tile[k4][h]);     u.y = f2bf(tile[k4 + 1][h]);
        u.z = f2bf(tile[k4 + 2][h]); u.w = f2bf(tile[k4 + 3][h]);
        *(ushort4*)(dst + (size_t)h * D_IN + k4) = u;
    }
}

// ------- router: 1 token/lane, D split across 4 waves; fused x->bf16 cast ---
__global__ __launch_bounds__(256)
void router_kernel(const float* __restrict__ x,
                   const float* __restrict__ Wr,
                   const float* __restrict__ br,
                   ushort_t* __restrict__ xb,
                   float* __restrict__ wslot,
                   int* __restrict__ entries,
                   int* __restrict__ cnt,
                   float* __restrict__ psum) {
    __shared__ float red[4][64][N_EXP];
    __shared__ int lcnt[N_EXP];
    __shared__ int gbase[N_EXP];

    int tid  = threadIdx.x;
    int lane = tid & 63;
    int wv   = tid >> 6;
    int t    = blockIdx.x * 64 + lane;

    if (wv == 1 && lane < N_EXP) lcnt[lane] = 0;

    const float* xrow = x + (size_t)t * D_IN + wv * 256;
    ushort_t* xbrow   = xb + (size_t)t * D_IN + wv * 256;
    const float* wrp  = Wr + wv * 256 * N_EXP;

    float acc[N_EXP];
#pragma unroll
    for (int e = 0; e < N_EXP; ++e) acc[e] = 0.f;

#pragma unroll 8
    for (int i = 0; i < 256; i += 4) {
        float4 xv = *(const float4*)(xrow + i);
        ushort4 u;
        u.x = f2bf(xv.x); u.y = f2bf(xv.y);
        u.z = f2bf(xv.z); u.w = f2bf(xv.w);
        *(ushort4*)(xbrow + i) = u;
        const float* wr = wrp + i * N_EXP;
#pragma unroll
        for (int j = 0; j < 4; ++j) {
            float xj = (j == 0) ? xv.x : (j == 1) ? xv.y : (j == 2) ? xv.z : xv.w;
#pragma unroll
            for (int e = 0; e < N_EXP; ++e)
                acc[e] += xj * wr[j * N_EXP + e];
        }
    }
#pragma unroll
    for (int e = 0; e < N_EXP; ++e) red[wv][lane][e] = acc[e];
    __syncthreads();

    int i0 = 0, i1 = 1, lpos0 = 0, lpos1 = 0;
    if (wv == 0) {
        float p[N_EXP];
#pragma unroll
        for (int e = 0; e < N_EXP; ++e)
            p[e] = red[0][lane][e] + red[1][lane][e]
                 + red[2][lane][e] + red[3][lane][e] + br[e];
        float m = p[0];
#pragma unroll
        for (int e = 1; e < N_EXP; ++e) m = fmaxf(m, p[e]);
        float Z = 0.f;
#pragma unroll
        for (int e = 0; e < N_EXP; ++e) { p[e] = expf(p[e] - m); Z += p[e]; }
        float invZ = 1.f / Z;
#pragma unroll
        for (int e = 0; e < N_EXP; ++e) p[e] *= invZ;
        float b0 = p[0];
#pragma unroll
        for (int e = 1; e < N_EXP; ++e) if (p[e] > b0) { b0 = p[e]; i0 = e; }
        i1 = (i0 == 0) ? 1 : 0; float b1 = p[i1];
#pragma unroll
        for (int e = 0; e < N_EXP; ++e)
            if (e != i0 && p[e] > b1) { b1 = p[e]; i1 = e; }
        float denom = b0 + b1 + 1e-9f;
        float2 w01; w01.x = b0 / denom; w01.y = b1 / denom;
        *(float2*)(wslot + 2 * t) = w01;
#pragma unroll
        for (int e = 0; e < N_EXP; ++e) {
            float v = p[e];
#pragma unroll
            for (int off = 32; off; off >>= 1) v += __shfl_xor(v, off, 64);
            if (lane == 0) atomicAdd(&psum[e], v);
        }
        lpos0 = atomicAdd(&lcnt[i0], 1);
        lpos1 = atomicAdd(&lcnt[i1], 1);
    }
    __syncthreads();
    if (tid < N_EXP) gbase[tid] = atomicAdd(&cnt[tid], lcnt[tid]);
    __syncthreads();
    if (wv == 0) {
        entries[i0 * T_TOK + gbase[i0] + lpos0] = 2 * t;
        entries[i1 * T_TOK + gbase[i1] + lpos1] = 2 * t + 1;
    }
}

// ------- grouped GEMM: barrier-free K-loop, global->register MFMA feeds,
//         LDS only for coalesced epilogue; XCD-affinity (e = blockIdx & 7) ---
__global__ __launch_bounds__(256, 3)
void moe_gemm(const ushort_t* __restrict__ xb,
              const ushort_t* __restrict__ Webt,
              const float* __restrict__ be,
              const int* __restrict__ entries,
              const int* __restrict__ cnt,
              const float* __restrict__ wslot,
              ushort_t* __restrict__ yslot) {
    int idx  = blockIdx.x;
    int e    = idx & 7;          // XCD-affinity
    int rest = idx >> 3;
    int bn   = rest & 7;         // fast index: 8 bn-blocks share A rows in time
    int bm   = rest >> 3;
    int cnte = cnt[e];
    if (bm * BM >= cnte) return;

    int tid    = threadIdx.x;
    int lane   = tid & 63;
    int wv     = tid >> 6;
    int lane15 = lane & 15;
    int quad   = lane >> 4;
    int wm = (wv >> 1) * 64;     // 0 or 64
    int wn = (wv & 1) * 64;      // 0 or 64

    const int* epe = entries + e * T_TOK;

    // per-lane operand base pointers (A frag row = lane15, k = quad*8 + j)
    const ushort_t* aptr[4];
#pragma unroll
    for (int mi = 0; mi < 4; ++mi) {
        int grow = bm * BM + wm + mi * 16 + lane15;
        int cr = grow < cnte ? grow : cnte - 1;
        int tok = epe[cr] >> 1;
        aptr[mi] = xb + (size_t)tok * D_IN + quad * 8;
    }
    const ushort_t* bptr[4];
    const ushort_t* wbase = Webt + (size_t)e * D_IN * D_OUT + quad * 8;
#pragma unroll
    for (int ni = 0; ni < 4; ++ni) {
        int col = bn * BN + wn + ni * 16 + lane15;
        bptr[ni] = wbase + (size_t)col * D_IN;
    }

    f4v acc[4][4];
#pragma unroll
    for (int mi = 0; mi < 4; ++mi)
#pragma unroll
        for (int ni = 0; ni < 4; ++ni)
            acc[mi][ni] = (f4v){0.f, 0.f, 0.f, 0.f};

    // barrier-free K loop: compiler software-pipelines the per-lane loads
#pragma unroll 2
    for (int k0 = 0; k0 < D_IN; k0 += 32) {
        s8v a[4], b[4];
#pragma unroll
        for (int mi = 0; mi < 4; ++mi)
            a[mi] = *(const s8v*)(aptr[mi] + k0);
#pragma unroll
        for (int ni = 0; ni < 4; ++ni)
            b[ni] = *(const s8v*)(bptr[ni] + k0);
#pragma unroll
        for (int mi = 0; mi < 4; ++mi)
#pragma unroll
            for (int ni = 0; ni < 4; ++ni)
                acc[mi][ni] = __builtin_amdgcn_mfma_f32_16x16x32_bf16(
                    a[mi], b[ni], acc[mi][ni], 0, 0, 0);
    }

    // ---- epilogue: scale+bias in regs, stage tile in LDS, coalesced store --
    __shared__ ushort_t ot[BM][136];   // 136 shorts = 272 B row stride (16B mult)

#pragma unroll
    for (int mi = 0; mi < 4; ++mi) {
#pragma unroll
        for (int r = 0; r < 4; ++r) {
            int lrow = wm + mi * 16 + quad * 4 + r;
            int grow = bm * BM + lrow;
            int cr   = grow < cnte ? grow : cnte - 1;
            float w  = grow < cnte ? wslot[epe[cr]] : 0.f;
#pragma unroll
            for (int ni = 0; ni < 4; ++ni) {
                int lcol = wn + ni * 16 + lane15;
                float bev = be[e * D_OUT + bn * BN + lcol];
                ot[lrow][lcol] = f2bf(w * (acc[mi][ni][r] + bev));
            }
        }
    }
    __syncthreads();

    int row  = tid >> 1;          // 0..127
    int half = tid & 1;           // 0 or 1 (64-col halves)
    int grow = bm * BM + row;
    if (grow < cnte) {
        int ent = epe[grow];
        ushort_t* dst = yslot + (size_t)ent * D_OUT + bn * BN + half * 64;
        const ushort_t* srcr = &ot[row][half * 64];
#pragma unroll
        for (int j = 0; j < 8; ++j)
            *(s8v*)(dst + j * 8) = *(const s8v*)(srcr + j * 8);
    }
}

// ------- combine (+ fused aux): y[t] = ys[2t] + ys[2t+1] --------------------
__global__ void combine_kernel(const ushort_t* __restrict__ yslot,
                               const float* __restrict__ psum,
                               const int* __restrict__ cnt,
                               float* __restrict__ out) {
    size_t i = ((size_t)blockIdx.x * 256 + threadIdx.x) * 4;
    size_t t = i >> 10;
    size_t h = i & 1023;
    const ushort_t* p0 = yslot + (2 * t) * D_OUT + h;
    ushort4 a = *(const ushort4*)p0;
    ushort4 b = *(const ushort4*)(p0 + D_OUT);
    float4 o;
    o.x = bf2f(a.x) + bf2f(b.x);
    o.y = bf2f(a.y) + bf2f(b.y);
    o.z = bf2f(a.z) + bf2f(b.z);
    o.w = bf2f(a.w) + bf2f(b.w);
    *(float4*)(out + i) = o;
    if (i == 0) {
        float s = 0.f;
#pragma unroll
        for (int e = 0; e < N_EXP; ++e)
            s += (psum[e] / (float)T_TOK) * ((float)cnt[e] / (float)(T_TOK * 2));
        out[(size_t)T_TOK * D_OUT] = (float)N_EXP * s;
    }
}

extern "C" void kernel_launch(void* const* d_in, const int* in_sizes, int n_in,
                              void* d_out, int out_size, void* d_ws, size_t ws_size,
                              hipStream_t stream) {
    const float* x  = (const float*)d_in[0];
    const float* Wr = (const float*)d_in[1];
    const float* br = (const float*)d_in[2];
    const float* We = (const float*)d_in[3];
    const float* be = (const float*)d_in[4];
    float* out = (float*)d_out;

    char* ws = (char*)d_ws;
    ushort_t* xb      = (ushort_t*)(ws);                    // 16 MiB
    ushort_t* Webt    = (ushort_t*)(ws + 16777216);         // 16 MiB
    ushort_t* yslot   = (ushort_t*)(ws + 33554432);         // 32 MiB (bf16)
    int*      entries = (int*)(ws + 67108864);              // 256 KiB
    float*    wslot   = (float*)(ws + 67371008);            // 64 KiB
    float*    psum    = (float*)(ws + 67436544);            // 32 B
    int*      cnt     = (int*)(ws + 67436576);              // 32 B

    hipLaunchKernelGGL(cast_transpose_we, dim3(16, 16, 8), dim3(256), 0, stream,
                       We, Webt, cnt, psum);
    hipLaunchKernelGGL(router_kernel, dim3(128), dim3(256), 0, stream,
                       x, Wr, br, xb, wslot, entries, cnt, psum);
    hipLaunchKernelGGL(moe_gemm, dim3(4096), dim3(256), 0, stream,
                       xb, Webt, be, entries, cnt, wslot, yslot);
    hipLaunchKernelGGL(combine_kernel, dim3(8192), dim3(256), 0, stream,
                       yslot, psum, cnt, out);
}

// Round 6
// 215.224 us; speedup vs baseline: 1.5709x; 1.5709x over previous
//
#include <hip/hip_runtime.h>
#include <hip/hip_bf16.h>
#include <stdint.h>

#define T_TOK 8192
#define D_IN  1024
#define N_EXP 8
#define D_OUT 1024

#define BM 128
#define BN 128
#define BK 32

typedef short s8v __attribute__((ext_vector_type(8)));
typedef float f4v __attribute__((ext_vector_type(4)));
typedef unsigned short ushort_t;

__device__ __forceinline__ ushort_t f2bf(float f) {
    uint32_t u = __float_as_uint(f);
    uint32_t r = (u + 0x7fffu + ((u >> 16) & 1u)) >> 16;
    return (ushort_t)r;
}

__device__ __forceinline__ float bf2f(ushort_t u) {
    return __uint_as_float(((uint32_t)u) << 16);
}

__device__ __forceinline__ void async_copy16(const void* g, void* lds) {
    __builtin_amdgcn_global_load_lds(
        (const __attribute__((address_space(1))) unsigned int*)g,
        (__attribute__((address_space(3))) unsigned int*)lds,
        16, 0, 0);
}

// ------- cast + transpose We -> bf16 [E][DOUT][D]; block0 zeroes counters ---
__global__ void cast_transpose_we(const float* __restrict__ We,
                                  ushort_t* __restrict__ Webt,
                                  int* __restrict__ cnt,
                                  float* __restrict__ psum) {
    if (blockIdx.x == 0 && blockIdx.y == 0 && blockIdx.z == 0 &&
        threadIdx.x < N_EXP) {
        cnt[threadIdx.x] = 0;
        psum[threadIdx.x] = 0.f;
    }
    __shared__ float tile[64][65];
    int e  = blockIdx.z;
    int k0 = blockIdx.y * 64;   // D index
    int h0 = blockIdx.x * 64;   // DOUT index
    int tid = threadIdx.x;
    const float* src = We + ((size_t)e * D_IN + k0) * D_OUT + h0;
#pragma unroll
    for (int it = 0; it < 4; ++it) {
        int lin = it * 256 + tid;
        int r = lin >> 4;
        int c4 = (lin & 15) * 4;
        float4 v = *(const float4*)(src + (size_t)r * D_OUT + c4);
        tile[r][c4]     = v.x; tile[r][c4 + 1] = v.y;
        tile[r][c4 + 2] = v.z; tile[r][c4 + 3] = v.w;
    }
    __syncthreads();
    ushort_t* dst = Webt + ((size_t)e * D_OUT + h0) * D_IN + k0;
#pragma unroll
    for (int it = 0; it < 4; ++it) {
        int lin = it * 256 + tid;
        int h = lin >> 4;
        int k4 = (lin & 15) * 4;
        ushort4 u;
        u.x = f2bf(tile[k4][h]);     u.y = f2bf(tile[k4 + 1][h]);
        u.z = f2bf(tile[k4 + 2][h]); u.w = f2bf(tile[k4 + 3][h]);
        *(ushort4*)(dst + (size_t)h * D_IN + k4) = u;
    }
}

// ------- logits + cast: one block per token, fully coalesced ----------------
__global__ __launch_bounds__(256)
void logits_cast(const float* __restrict__ x,
                 const float* __restrict__ Wr,
                 const float* __restrict__ br,
                 ushort_t* __restrict__ xb,
                 float* __restrict__ logits) {
    __shared__ float red[4][N_EXP];
    int t    = blockIdx.x;
    int tid  = threadIdx.x;
    int lane = tid & 63;
    int wv   = tid >> 6;

    float4 xv = *(const float4*)(x + (size_t)t * D_IN + tid * 4);
    ushort4 u;
    u.x = f2bf(xv.x); u.y = f2bf(xv.y);
    u.z = f2bf(xv.z); u.w = f2bf(xv.w);
    *(ushort4*)(xb + (size_t)t * D_IN + tid * 4) = u;

    const float* wr = Wr + (size_t)tid * 4 * N_EXP;   // 128B/thread, coalesced
    float acc[N_EXP];
#pragma unroll
    for (int e = 0; e < N_EXP; ++e) acc[e] = 0.f;
#pragma unroll
    for (int j = 0; j < 4; ++j) {
        float xj = (j == 0) ? xv.x : (j == 1) ? xv.y : (j == 2) ? xv.z : xv.w;
#pragma unroll
        for (int e = 0; e < N_EXP; ++e)
            acc[e] += xj * wr[j * N_EXP + e];
    }
#pragma unroll
    for (int e = 0; e < N_EXP; ++e) {
#pragma unroll
        for (int off = 32; off; off >>= 1) acc[e] += __shfl_xor(acc[e], off, 64);
    }
    if (lane == 0) {
#pragma unroll
        for (int e = 0; e < N_EXP; ++e) red[wv][e] = acc[e];
    }
    __syncthreads();
    if (tid < N_EXP)
        logits[(size_t)t * N_EXP + tid] =
            red[0][tid] + red[1][tid] + red[2][tid] + red[3][tid] + br[tid];
}

// ------- route: softmax + top2 + expert lists (1 token per thread) ----------
__global__ __launch_bounds__(256)
void route_kernel(const float* __restrict__ logits,
                  float* __restrict__ wslot,
                  int* __restrict__ entries,
                  int* __restrict__ cnt,
                  float* __restrict__ psum) {
    __shared__ int lcnt[N_EXP];
    __shared__ int gbase[N_EXP];
    __shared__ float lps[N_EXP];
    int tid  = threadIdx.x;
    int lane = tid & 63;
    int t    = blockIdx.x * 256 + tid;
    if (tid < N_EXP) { lcnt[tid] = 0; lps[tid] = 0.f; }
    __syncthreads();

    float p[N_EXP];
    float4 l0 = *(const float4*)(logits + (size_t)t * N_EXP);
    float4 l1 = *(const float4*)(logits + (size_t)t * N_EXP + 4);
    p[0] = l0.x; p[1] = l0.y; p[2] = l0.z; p[3] = l0.w;
    p[4] = l1.x; p[5] = l1.y; p[6] = l1.z; p[7] = l1.w;

    float m = p[0];
#pragma unroll
    for (int e = 1; e < N_EXP; ++e) m = fmaxf(m, p[e]);
    float Z = 0.f;
#pragma unroll
    for (int e = 0; e < N_EXP; ++e) { p[e] = expf(p[e] - m); Z += p[e]; }
    float invZ = 1.f / Z;
#pragma unroll
    for (int e = 0; e < N_EXP; ++e) p[e] *= invZ;

    // psum partial: wave-reduce then 8 LDS atomics per wave
#pragma unroll
    for (int e = 0; e < N_EXP; ++e) {
        float v = p[e];
#pragma unroll
        for (int off = 32; off; off >>= 1) v += __shfl_xor(v, off, 64);
        if (lane == 0) atomicAdd(&lps[e], v);
    }

    // top-2, lowest index wins ties (strict >)
    int i0 = 0; float b0 = p[0];
#pragma unroll
    for (int e = 1; e < N_EXP; ++e) if (p[e] > b0) { b0 = p[e]; i0 = e; }
    int i1 = (i0 == 0) ? 1 : 0; float b1 = p[i1];
#pragma unroll
    for (int e = 0; e < N_EXP; ++e)
        if (e != i0 && p[e] > b1) { b1 = p[e]; i1 = e; }
    float denom = b0 + b1 + 1e-9f;
    float2 w01; w01.x = b0 / denom; w01.y = b1 / denom;
    *(float2*)(wslot + 2 * t) = w01;

    int lpos0 = atomicAdd(&lcnt[i0], 1);
    int lpos1 = atomicAdd(&lcnt[i1], 1);
    __syncthreads();
    if (tid < N_EXP) {
        gbase[tid] = atomicAdd(&cnt[tid], lcnt[tid]);
        atomicAdd(&psum[tid], lps[tid]);
    }
    __syncthreads();
    entries[i0 * T_TOK + gbase[i0] + lpos0] = 2 * t;
    entries[i1 * T_TOK + gbase[i1] + lpos1] = 2 * t + 1;
}

// ------- grouped GEMM, 128x128, dbuf LDS staging, XOR swizzle, XCD affinity,
//         LDS-staged coalesced bf16 epilogue (aliased over K-loop buffers) ---
__global__ __launch_bounds__(256, 3)
void moe_gemm(const ushort_t* __restrict__ xb,
              const ushort_t* __restrict__ Webt,
              const float* __restrict__ be,
              const int* __restrict__ entries,
              const int* __restrict__ cnt,
              const float* __restrict__ wslot,
              ushort_t* __restrict__ yslot) {
    int idx  = blockIdx.x;
    int e    = idx & 7;          // XCD-affinity: round-robin block->XCD
    int rest = idx >> 3;
    int bn   = rest & 7;
    int bm   = rest >> 3;
    int cnte = cnt[e];
    if (bm * BM >= cnte) return;

    // union: K-loop staging (32 KB) and output tile (34 KB) share LDS
    __shared__ __attribute__((aligned(16))) char smem[34816];
    ushort_t* As0 = (ushort_t*)smem;            // [2][4096]
    ushort_t* Bs0 = (ushort_t*)(smem + 16384);  // [2][4096]

    int tid    = threadIdx.x;
    int lane   = tid & 63;
    int wv     = tid >> 6;
    int lane15 = lane & 15;
    int quad   = lane >> 4;
    int wm = (wv >> 1) * 64;
    int wn = (wv & 1) * 64;

    // staging addresses (chunk XOR-swizzle to kill LDS read conflicts)
    int rA   = tid >> 2;
    int cper = (tid & 3) ^ ((rA >> 1) & 3);
    const int* epe = entries + e * T_TOK;
    int r0 = bm * BM + rA;
    int r1 = r0 + 64;
    int c0 = r0 < cnte ? r0 : cnte - 1;
    int c1 = r1 < cnte ? r1 : cnte - 1;
    int tok0 = epe[c0] >> 1;
    int tok1 = epe[c1] >> 1;
    const ushort_t* gA0 = xb + (size_t)tok0 * D_IN + cper * 8;
    const ushort_t* gA1 = xb + (size_t)tok1 * D_IN + cper * 8;
    const ushort_t* WB  = Webt + (size_t)e * D_IN * D_OUT + cper * 8;
    const ushort_t* gB0 = WB + (size_t)(bn * BN + rA) * D_IN;
    const ushort_t* gB1 = WB + (size_t)(bn * BN + rA + 64) * D_IN;
    int ldsOff = wv * 1024;

    // fragment read offsets (mirror the XOR swizzle)
    int aoff[4], boff[4];
#pragma unroll
    for (int mi = 0; mi < 4; ++mi) {
        int m = wm + mi * 16 + lane15;
        aoff[mi] = m * 64 + (quad ^ ((m >> 1) & 3)) * 16;
        int n = wn + mi * 16 + lane15;
        boff[mi] = n * 64 + (quad ^ ((n >> 1) & 3)) * 16;
    }

    f4v acc[4][4];
#pragma unroll
    for (int mi = 0; mi < 4; ++mi)
#pragma unroll
        for (int ni = 0; ni < 4; ++ni)
            acc[mi][ni] = (f4v){0.f, 0.f, 0.f, 0.f};

    // prologue: stage k0 = 0 into buffer 0
    async_copy16(gA0, (char*)As0 + ldsOff);
    async_copy16(gA1, (char*)As0 + 4096 + ldsOff);
    async_copy16(gB0, (char*)Bs0 + ldsOff);
    async_copy16(gB1, (char*)Bs0 + 4096 + ldsOff);

    for (int k0 = 0; k0 < D_IN; k0 += BK) {
        int cur = (k0 >> 5) & 1;
        __syncthreads();                    // drains loads into buf[cur]
        if (k0 + BK < D_IN) {
            int nxt = cur ^ 1;
            async_copy16(gA0 + k0 + BK, (char*)As0 + nxt * 8192 + ldsOff);
            async_copy16(gA1 + k0 + BK, (char*)As0 + nxt * 8192 + 4096 + ldsOff);
            async_copy16(gB0 + k0 + BK, (char*)Bs0 + nxt * 8192 + ldsOff);
            async_copy16(gB1 + k0 + BK, (char*)Bs0 + nxt * 8192 + 4096 + ldsOff);
        }
        const char* ab = (const char*)As0 + cur * 8192;
        const char* bb = (const char*)Bs0 + cur * 8192;
        s8v a[4], b[4];
#pragma unroll
        for (int mi = 0; mi < 4; ++mi) a[mi] = *(const s8v*)(ab + aoff[mi]);
#pragma unroll
        for (int ni = 0; ni < 4; ++ni) b[ni] = *(const s8v*)(bb + boff[ni]);
#pragma unroll
        for (int mi = 0; mi < 4; ++mi)
#pragma unroll
            for (int ni = 0; ni < 4; ++ni)
                acc[mi][ni] = __builtin_amdgcn_mfma_f32_16x16x32_bf16(
                    a[mi], b[ni], acc[mi][ni], 0, 0, 0);
    }

    // ---- epilogue: scale+bias, stage tile in LDS (aliased), coalesced store -
    __syncthreads();   // all ds_reads done before smem is reused as ot
    ushort_t (*ot)[136] = (ushort_t(*)[136])smem;

#pragma unroll
    for (int mi = 0; mi < 4; ++mi) {
#pragma unroll
        for (int r = 0; r < 4; ++r) {
            int lrow = wm + mi * 16 + quad * 4 + r;
            int grow = bm * BM + lrow;
            int cr   = grow < cnte ? grow : cnte - 1;
            float w  = grow < cnte ? wslot[epe[cr]] : 0.f;
#pragma unroll
            for (int ni = 0; ni < 4; ++ni) {
                int lcol = wn + ni * 16 + lane15;
                float bev = be[e * D_OUT + bn * BN + lcol];
                ot[lrow][lcol] = f2bf(w * (acc[mi][ni][r] + bev));
            }
        }
    }
    __syncthreads();

    int row  = tid >> 1;
    int half = tid & 1;
    int grow = bm * BM + row;
    if (grow < cnte) {
        int ent = epe[grow];
        ushort_t* dst = yslot + (size_t)ent * D_OUT + bn * BN + half * 64;
        const ushort_t* srcr = &ot[row][half * 64];
#pragma unroll
        for (int j = 0; j < 8; ++j)
            *(s8v*)(dst + j * 8) = *(const s8v*)(srcr + j * 8);
    }
}

// ------- combine (+ fused aux): y[t] = ys[2t] + ys[2t+1] --------------------
__global__ void combine_kernel(const ushort_t* __restrict__ yslot,
                               const float* __restrict__ psum,
                               const int* __restrict__ cnt,
                               float* __restrict__ out) {
    size_t i = ((size_t)blockIdx.x * 256 + threadIdx.x) * 4;
    size_t t = i >> 10;
    size_t h = i & 1023;
    const ushort_t* p0 = yslot + (2 * t) * D_OUT + h;
    ushort4 a = *(const ushort4*)p0;
    ushort4 b = *(const ushort4*)(p0 + D_OUT);
    float4 o;
    o.x = bf2f(a.x) + bf2f(b.x);
    o.y = bf2f(a.y) + bf2f(b.y);
    o.z = bf2f(a.z) + bf2f(b.z);
    o.w = bf2f(a.w) + bf2f(b.w);
    *(float4*)(out + i) = o;
    if (i == 0) {
        float s = 0.f;
#pragma unroll
        for (int e = 0; e < N_EXP; ++e)
            s += (psum[e] / (float)T_TOK) * ((float)cnt[e] / (float)(T_TOK * 2));
        out[(size_t)T_TOK * D_OUT] = (float)N_EXP * s;
    }
}

extern "C" void kernel_launch(void* const* d_in, const int* in_sizes, int n_in,
                              void* d_out, int out_size, void* d_ws, size_t ws_size,
                              hipStream_t stream) {
    const float* x  = (const float*)d_in[0];
    const float* Wr = (const float*)d_in[1];
    const float* br = (const float*)d_in[2];
    const float* We = (const float*)d_in[3];
    const float* be = (const float*)d_in[4];
    float* out = (float*)d_out;

    char* ws = (char*)d_ws;
    ushort_t* xb      = (ushort_t*)(ws);                    // 16 MiB
    ushort_t* Webt    = (ushort_t*)(ws + 16777216);         // 16 MiB
    ushort_t* yslot   = (ushort_t*)(ws + 33554432);         // 32 MiB (bf16)
    int*      entries = (int*)(ws + 67108864);              // 256 KiB
    float*    wslot   = (float*)(ws + 67371008);            // 64 KiB
    float*    logits  = (float*)(ws + 67436544);            // 256 KiB
    float*    psum    = (float*)(ws + 67698688);            // 32 B
    int*      cnt     = (int*)(ws + 67698720);              // 32 B

    hipLaunchKernelGGL(cast_transpose_we, dim3(16, 16, 8), dim3(256), 0, stream,
                       We, Webt, cnt, psum);
    hipLaunchKernelGGL(logits_cast, dim3(T_TOK), dim3(256), 0, stream,
                       x, Wr, br, xb, logits);
    hipLaunchKernelGGL(route_kernel, dim3(32), dim3(256), 0, stream,
                       logits, wslot, entries, cnt, psum);
    hipLaunchKernelGGL(moe_gemm, dim3(4096), dim3(256), 0, stream,
                       xb, Webt, be, entries, cnt, wslot, yslot);
    hipLaunchKernelGGL(combine_kernel, dim3(8192), dim3(256), 0, stream,
                       yslot, psum, cnt, out);
}

// Round 8
// 206.515 us; speedup vs baseline: 1.6372x; 1.0422x over previous
//
#include <hip/hip_runtime.h>
#include <hip/hip_bf16.h>
#include <stdint.h>

#define T_TOK 8192
#define D_IN  1024
#define N_EXP 8
#define D_OUT 1024

#define BM 128
#define BN 128
#define BK 32

typedef short s8v __attribute__((ext_vector_type(8)));
typedef float f4v __attribute__((ext_vector_type(4)));
typedef unsigned short ushort_t;

__device__ __forceinline__ ushort_t f2bf(float f) {
    uint32_t u = __float_as_uint(f);
    uint32_t r = (u + 0x7fffu + ((u >> 16) & 1u)) >> 16;
    return (ushort_t)r;
}

__device__ __forceinline__ float bf2f(ushort_t u) {
    return __uint_as_float(((uint32_t)u) << 16);
}

__device__ __forceinline__ void async_copy16(const void* g, void* lds) {
    __builtin_amdgcn_global_load_lds(
        (const __attribute__((address_space(1))) unsigned int*)g,
        (__attribute__((address_space(3))) unsigned int*)lds,
        16, 0, 0);
}

// Fenced pipeline barrier: memory clobber stops the compiler from moving any
// LDS/global op across it; lgkmcnt(0) guarantees own ds_reads completed
// before passing the barrier (inter-wave buffer-reuse safety).
#define PIPE_BARRIER_VM4() \
    asm volatile("s_waitcnt vmcnt(4) lgkmcnt(0)\n\ts_barrier" ::: "memory")
#define PIPE_BARRIER_VM0() \
    asm volatile("s_waitcnt vmcnt(0) lgkmcnt(0)\n\ts_barrier" ::: "memory")

// ------- fused prep: [0,T_TOK) logits+x-cast; [T_TOK,..) We transpose -------
__global__ __launch_bounds__(256)
void prep_kernel(const float* __restrict__ x,
                 const float* __restrict__ Wr,
                 const float* __restrict__ br,
                 const float* __restrict__ We,
                 ushort_t* __restrict__ xb,
                 ushort_t* __restrict__ Webt,
                 float* __restrict__ logits,
                 int* __restrict__ cnt,
                 float* __restrict__ psum) {
    __shared__ float red[4][N_EXP];
    __shared__ float tile[64][65];
    int bid = blockIdx.x;
    int tid = threadIdx.x;

    if (bid < T_TOK) {
        int t    = bid;
        int lane = tid & 63;
        int wv   = tid >> 6;

        float4 xv = *(const float4*)(x + (size_t)t * D_IN + tid * 4);
        ushort4 u;
        u.x = f2bf(xv.x); u.y = f2bf(xv.y);
        u.z = f2bf(xv.z); u.w = f2bf(xv.w);
        *(ushort4*)(xb + (size_t)t * D_IN + tid * 4) = u;

        const float* wr = Wr + (size_t)tid * 4 * N_EXP;
        float acc[N_EXP];
#pragma unroll
        for (int e = 0; e < N_EXP; ++e) acc[e] = 0.f;
#pragma unroll
        for (int j = 0; j < 4; ++j) {
            float xj = (j == 0) ? xv.x : (j == 1) ? xv.y : (j == 2) ? xv.z : xv.w;
#pragma unroll
            for (int e = 0; e < N_EXP; ++e)
                acc[e] += xj * wr[j * N_EXP + e];
        }
#pragma unroll
        for (int e = 0; e < N_EXP; ++e) {
#pragma unroll
            for (int off = 32; off; off >>= 1)
                acc[e] += __shfl_xor(acc[e], off, 64);
        }
        if (lane == 0) {
#pragma unroll
            for (int e = 0; e < N_EXP; ++e) red[wv][e] = acc[e];
        }
        __syncthreads();
        if (tid < N_EXP)
            logits[(size_t)t * N_EXP + tid] =
                red[0][tid] + red[1][tid] + red[2][tid] + red[3][tid] + br[tid];
    } else {
        int b  = bid - T_TOK;          // 0..2047
        int e  = b >> 8;
        int k0 = ((b >> 4) & 15) * 64; // D index
        int h0 = (b & 15) * 64;        // DOUT index
        if (b == 0 && tid < N_EXP) { cnt[tid] = 0; psum[tid] = 0.f; }

        const float* src = We + ((size_t)e * D_IN + k0) * D_OUT + h0;
#pragma unroll
        for (int it = 0; it < 4; ++it) {
            int lin = it * 256 + tid;
            int r = lin >> 4;
            int c4 = (lin & 15) * 4;
            float4 v = *(const float4*)(src + (size_t)r * D_OUT + c4);
            tile[r][c4]     = v.x; tile[r][c4 + 1] = v.y;
            tile[r][c4 + 2] = v.z; tile[r][c4 + 3] = v.w;
        }
        __syncthreads();
        ushort_t* dst = Webt + ((size_t)e * D_OUT + h0) * D_IN + k0;
#pragma unroll
        for (int it = 0; it < 4; ++it) {
            int lin = it * 256 + tid;
            int h = lin >> 4;
            int k4 = (lin & 15) * 4;
            ushort4 u;
            u.x = f2bf(tile[k4][h]);     u.y = f2bf(tile[k4 + 1][h]);
            u.z = f2bf(tile[k4 + 2][h]); u.w = f2bf(tile[k4 + 3][h]);
            *(ushort4*)(dst + (size_t)h * D_IN + k4) = u;
        }
    }
}

// ------- route: softmax + top2 + expert lists (1 token per thread) ----------
__global__ __launch_bounds__(256)
void route_kernel(const float* __restrict__ logits,
                  float* __restrict__ wslot,
                  int* __restrict__ entries,
                  int* __restrict__ cnt,
                  float* __restrict__ psum) {
    __shared__ int lcnt[N_EXP];
    __shared__ int gbase[N_EXP];
    __shared__ float lps[N_EXP];
    int tid  = threadIdx.x;
    int lane = tid & 63;
    int t    = blockIdx.x * 256 + tid;
    if (tid < N_EXP) { lcnt[tid] = 0; lps[tid] = 0.f; }
    __syncthreads();

    float p[N_EXP];
    float4 l0 = *(const float4*)(logits + (size_t)t * N_EXP);
    float4 l1 = *(const float4*)(logits + (size_t)t * N_EXP + 4);
    p[0] = l0.x; p[1] = l0.y; p[2] = l0.z; p[3] = l0.w;
    p[4] = l1.x; p[5] = l1.y; p[6] = l1.z; p[7] = l1.w;

    float m = p[0];
#pragma unroll
    for (int e = 1; e < N_EXP; ++e) m = fmaxf(m, p[e]);
    float Z = 0.f;
#pragma unroll
    for (int e = 0; e < N_EXP; ++e) { p[e] = expf(p[e] - m); Z += p[e]; }
    float invZ = 1.f / Z;
#pragma unroll
    for (int e = 0; e < N_EXP; ++e) p[e] *= invZ;

#pragma unroll
    for (int e = 0; e < N_EXP; ++e) {
        float v = p[e];
#pragma unroll
        for (int off = 32; off; off >>= 1) v += __shfl_xor(v, off, 64);
        if (lane == 0) atomicAdd(&lps[e], v);
    }

    int i0 = 0; float b0 = p[0];
#pragma unroll
    for (int e = 1; e < N_EXP; ++e) if (p[e] > b0) { b0 = p[e]; i0 = e; }
    int i1 = (i0 == 0) ? 1 : 0; float b1 = p[i1];
#pragma unroll
    for (int e = 0; e < N_EXP; ++e)
        if (e != i0 && p[e] > b1) { b1 = p[e]; i1 = e; }
    float denom = b0 + b1 + 1e-9f;
    float2 w01; w01.x = b0 / denom; w01.y = b1 / denom;
    *(float2*)(wslot + 2 * t) = w01;

    int lpos0 = atomicAdd(&lcnt[i0], 1);
    int lpos1 = atomicAdd(&lcnt[i1], 1);
    __syncthreads();
    if (tid < N_EXP) {
        gbase[tid] = atomicAdd(&cnt[tid], lcnt[tid]);
        atomicAdd(&psum[tid], lps[tid]);
    }
    __syncthreads();
    entries[i0 * T_TOK + gbase[i0] + lpos0] = 2 * t;
    entries[i1 * T_TOK + gbase[i1] + lpos1] = 2 * t + 1;
}

// ------- grouped GEMM, 128x128, 3-deep LDS pipeline with FENCED
//         s_waitcnt vmcnt(4)+s_barrier (never full drain), XOR swizzle,
//         XCD affinity, LDS-staged coalesced bf16 epilogue ------------------
__global__ __launch_bounds__(256, 3)
void moe_gemm(const ushort_t* __restrict__ xb,
              const ushort_t* __restrict__ Webt,
              const float* __restrict__ be,
              const int* __restrict__ entries,
              const int* __restrict__ cnt,
              const float* __restrict__ wslot,
              ushort_t* __restrict__ yslot) {
    int idx  = blockIdx.x;
    int e    = idx & 7;          // XCD-affinity: round-robin block->XCD
    int rest = idx >> 3;
    int bn   = rest & 7;
    int bm   = rest >> 3;
    int cnte = cnt[e];
    if (bm * BM >= cnte) return;

    // 3 pipeline buffers x (As 8KB + Bs 8KB) = 48 KB; epilogue tile aliases
    __shared__ __attribute__((aligned(16))) char smem[3 * 16384];

    int tid    = threadIdx.x;
    int lane   = tid & 63;
    int wv     = tid >> 6;
    int lane15 = lane & 15;
    int quad   = lane >> 4;
    int wm = (wv >> 1) * 64;
    int wn = (wv & 1) * 64;

    // staging addresses (chunk XOR-swizzle to kill LDS read conflicts)
    int rA   = tid >> 2;
    int cper = (tid & 3) ^ ((rA >> 1) & 3);
    const int* epe = entries + e * T_TOK;
    int r0 = bm * BM + rA;
    int r1 = r0 + 64;
    int c0 = r0 < cnte ? r0 : cnte - 1;
    int c1 = r1 < cnte ? r1 : cnte - 1;
    int tok0 = epe[c0] >> 1;
    int tok1 = epe[c1] >> 1;
    const ushort_t* gA0 = xb + (size_t)tok0 * D_IN + cper * 8;
    const ushort_t* gA1 = xb + (size_t)tok1 * D_IN + cper * 8;
    const ushort_t* WB  = Webt + (size_t)e * D_IN * D_OUT + cper * 8;
    const ushort_t* gB0 = WB + (size_t)(bn * BN + rA) * D_IN;
    const ushort_t* gB1 = WB + (size_t)(bn * BN + rA + 64) * D_IN;
    int ldsOff = wv * 1024;

    // fragment read offsets (mirror the XOR swizzle)
    int aoff[4], boff[4];
#pragma unroll
    for (int mi = 0; mi < 4; ++mi) {
        int m = wm + mi * 16 + lane15;
        aoff[mi] = m * 64 + (quad ^ ((m >> 1) & 3)) * 16;
        int n = wn + mi * 16 + lane15;
        boff[mi] = n * 64 + (quad ^ ((n >> 1) & 3)) * 16;
    }

    f4v acc[4][4];
#pragma unroll
    for (int mi = 0; mi < 4; ++mi)
#pragma unroll
        for (int ni = 0; ni < 4; ++ni)
            acc[mi][ni] = (f4v){0.f, 0.f, 0.f, 0.f};

#define STAGE(ti)                                                          \
    do {                                                                   \
        char* _b = smem + ((ti) % 3) * 16384;                              \
        int _k = (ti) * BK;                                                \
        async_copy16(gA0 + _k, _b + ldsOff);                               \
        async_copy16(gA1 + _k, _b + 4096 + ldsOff);                        \
        async_copy16(gB0 + _k, _b + 8192 + ldsOff);                        \
        async_copy16(gB1 + _k, _b + 12288 + ldsOff);                       \
    } while (0)

#define COMPUTE(ti)                                                        \
    do {                                                                   \
        const char* ab = smem + ((ti) % 3) * 16384;                        \
        const char* bb = ab + 8192;                                        \
        s8v a[4], b[4];                                                    \
        _Pragma("unroll")                                                  \
        for (int mi = 0; mi < 4; ++mi) a[mi] = *(const s8v*)(ab + aoff[mi]); \
        _Pragma("unroll")                                                  \
        for (int ni = 0; ni < 4; ++ni) b[ni] = *(const s8v*)(bb + boff[ni]); \
        _Pragma("unroll")                                                  \
        for (int mi = 0; mi < 4; ++mi)                                     \
            _Pragma("unroll")                                              \
            for (int ni = 0; ni < 4; ++ni)                                 \
                acc[mi][ni] = __builtin_amdgcn_mfma_f32_16x16x32_bf16(     \
                    a[mi], b[ni], acc[mi][ni], 0, 0, 0);                   \
    } while (0)

    // prologue: tiles 0 and 1 in flight
    STAGE(0);
    STAGE(1);

    // main loop: wait for tile i (keep tile i+1's 4 loads in flight),
    // prefetch tile i+2, compute tile i.  NT = 1024/32 = 32 tiles.
    for (int i = 0; i < 30; ++i) {
        PIPE_BARRIER_VM4();
        STAGE(i + 2);
        COMPUTE(i);
    }
    PIPE_BARRIER_VM4();   // tile 30 ready (31 still in flight)
    COMPUTE(30);
    PIPE_BARRIER_VM0();   // tile 31 ready
    COMPUTE(31);

    // ---- epilogue: scale+bias, stage tile in LDS (aliased), coalesced store
    __syncthreads();   // all ds_reads done before smem is reused as ot
    ushort_t (*ot)[136] = (ushort_t(*)[136])smem;

#pragma unroll
    for (int mi = 0; mi < 4; ++mi) {
#pragma unroll
        for (int r = 0; r < 4; ++r) {
            int lrow = wm + mi * 16 + quad * 4 + r;
            int grow = bm * BM + lrow;
            int cr   = grow < cnte ? grow : cnte - 1;
            float w  = grow < cnte ? wslot[epe[cr]] : 0.f;
#pragma unroll
            for (int ni = 0; ni < 4; ++ni) {
                int lcol = wn + ni * 16 + lane15;
                float bev = be[e * D_OUT + bn * BN + lcol];
                ot[lrow][lcol] = f2bf(w * (acc[mi][ni][r] + bev));
            }
        }
    }
    __syncthreads();

    int row  = tid >> 1;
    int half = tid & 1;
    int grow = bm * BM + row;
    if (grow < cnte) {
        int ent = epe[grow];
        ushort_t* dst = yslot + (size_t)ent * D_OUT + bn * BN + half * 64;
        const ushort_t* srcr = &ot[row][half * 64];
#pragma unroll
        for (int j = 0; j < 8; ++j)
            *(s8v*)(dst + j * 8) = *(const s8v*)(srcr + j * 8);
    }
}

// ------- combine (+ fused aux): y[t] = ys[2t] + ys[2t+1] --------------------
__global__ void combine_kernel(const ushort_t* __restrict__ yslot,
                               const float* __restrict__ psum,
                               const int* __restrict__ cnt,
                               float* __restrict__ out) {
    size_t i = ((size_t)blockIdx.x * 256 + threadIdx.x) * 4;
    size_t t = i >> 10;
    size_t h = i & 1023;
    const ushort_t* p0 = yslot + (2 * t) * D_OUT + h;
    ushort4 a = *(const ushort4*)p0;
    ushort4 b = *(const ushort4*)(p0 + D_OUT);
    float4 o;
    o.x = bf2f(a.x) + bf2f(b.x);
    o.y = bf2f(a.y) + bf2f(b.y);
    o.z = bf2f(a.z) + bf2f(b.z);
    o.w = bf2f(a.w) + bf2f(b.w);
    *(float4*)(out + i) = o;
    if (i == 0) {
        float s = 0.f;
#pragma unroll
        for (int e = 0; e < N_EXP; ++e)
            s += (psum[e] / (float)T_TOK) * ((float)cnt[e] / (float)(T_TOK * 2));
        out[(size_t)T_TOK * D_OUT] = (float)N_EXP * s;
    }
}

extern "C" void kernel_launch(void* const* d_in, const int* in_sizes, int n_in,
                              void* d_out, int out_size, void* d_ws, size_t ws_size,
                              hipStream_t stream) {
    const float* x  = (const float*)d_in[0];
    const float* Wr = (const float*)d_in[1];
    const float* br = (const float*)d_in[2];
    const float* We = (const float*)d_in[3];
    const float* be = (const float*)d_in[4];
    float* out = (float*)d_out;

    char* ws = (char*)d_ws;
    ushort_t* xb      = (ushort_t*)(ws);                    // 16 MiB
    ushort_t* Webt    = (ushort_t*)(ws + 16777216);         // 16 MiB
    ushort_t* yslot   = (ushort_t*)(ws + 33554432);         // 32 MiB (bf16)
    int*      entries = (int*)(ws + 67108864);              // 256 KiB
    float*    wslot   = (float*)(ws + 67371008);            // 64 KiB
    float*    logits  = (float*)(ws + 67436544);            // 256 KiB
    float*    psum    = (float*)(ws + 67698688);            // 32 B
    int*      cnt     = (int*)(ws + 67698720);              // 32 B

    hipLaunchKernelGGL(prep_kernel, dim3(T_TOK + 2048), dim3(256), 0, stream,
                       x, Wr, br, We, xb, Webt, logits, cnt, psum);
    hipLaunchKernelGGL(route_kernel, dim3(32), dim3(256), 0, stream,
                       logits, wslot, entries, cnt, psum);
    hipLaunchKernelGGL(moe_gemm, dim3(4096), dim3(256), 0, stream,
                       xb, Webt, be, entries, cnt, wslot, yslot);
    hipLaunchKernelGGL(combine_kernel, dim3(8192), dim3(256), 0, stream,
                       yslot, psum, cnt, out);
}